// Round 1
// 357.296 us; speedup vs baseline: 1.0830x; 1.0830x over previous
//
#include <hip/hip_runtime.h>
#include <math.h>

#define B 2
#define S 1024
#define E 2048
#define H 16
#define HD 128
#define ROT 64
#define EPSN 1e-12f

using half8 = __attribute__((ext_vector_type(8))) _Float16;
using half4 = __attribute__((ext_vector_type(4))) _Float16;
using half2 = __attribute__((ext_vector_type(2))) _Float16;
using f32x4 = __attribute__((ext_vector_type(4))) float;

// async global->LDS, 16B per lane; LDS dest = wave-uniform base + lane*16
__device__ __forceinline__ void gl_lds16(const void* g, void* l) {
    __builtin_amdgcn_global_load_lds(
        (const __attribute__((address_space(1))) unsigned int*)g,
        (__attribute__((address_space(3))) unsigned int*)l, 16, 0, 0);
}

#define BARX()  asm volatile("s_barrier" ::: "memory")
#define LGKM0() asm volatile("s_waitcnt lgkmcnt(0)" ::: "memory")
#define VMW(n)  asm volatile("s_waitcnt vmcnt(" #n ")" ::: "memory")

// ---------------------------------------------------------------------------
// Batched fp32 -> fp16: 5 tensors, each exactly B*S*E = E*E = 4M elements.
// ---------------------------------------------------------------------------
__global__ __launch_bounds__(256) void f2h5(const float* __restrict__ x0,
                                            const float* __restrict__ x1,
                                            const float* __restrict__ x2,
                                            const float* __restrict__ x3,
                                            const float* __restrict__ x4,
                                            _Float16* __restrict__ y0,
                                            _Float16* __restrict__ y1,
                                            _Float16* __restrict__ y2,
                                            _Float16* __restrict__ y3,
                                            _Float16* __restrict__ y4) {
    const float* xs[5] = {x0, x1, x2, x3, x4};
    _Float16*    ys[5] = {y0, y1, y2, y3, y4};
    const int t = blockIdx.y;
    const int i = blockIdx.x * 256 + threadIdx.x;
    float4 v = ((const float4*)xs[t])[i];
    half4 h;
    h[0] = (_Float16)v.x; h[1] = (_Float16)v.y;
    h[2] = (_Float16)v.z; h[3] = (_Float16)v.w;
    ((half4*)ys[t])[i] = h;
}

// ---------------------------------------------------------------------------
// Fused QKV NT-GEMM, 256x256 tile, BK=64, 8-phase pipelined schedule.
// 512 thr = 8 waves (2M x 4N); per-wave output: 4 quadrants of 64x32 ->
// acc[2][2][4][2] 16x16 frags. LDS 128 KiB: slot(ab,db,hf)=ab*4+db*2+hf,
// each half-tile [128 rows][64 k] stored [rb(8)][q(8)][r(16)] uint4 so frag
// ds_read_b128 runs are linear (conflict-free, verified by current kernel's
// SQ_LDS_BANK_CONFLICT==0 with the same layout trick).
// Per phase: ds_read (4/8/12 b128) | stage one half-tile (2x gl_lds16) |
// [vmcnt(4) at ph3/ph7] | barrier | lgkmcnt(0) | setprio(1) 16 MFMA setprio(0)
// | barrier.  Gray quadrant order (0,0)(0,1)(1,1)(1,0): each phase reloads
// only one operand half. Every LDS slot is overwritten exactly one barrier
// after its last read; counted vmcnt(4) keeps 2 half-tiles in flight (never
// drains to 0 mid-loop; ph3 of the final iter drains since ph1-4 stages are
// skipped there and ph0's stage must land).
// Grid: 192 = 3 matrices x 8x8 tiles, bijective XCD swizzle (192%8==0).
// ---------------------------------------------------------------------------
__global__ __launch_bounds__(512, 2) void gemm_qkv256(
        const _Float16* __restrict__ hs,
        const _Float16* __restrict__ wq,
        const _Float16* __restrict__ wk,
        const _Float16* __restrict__ wv,
        _Float16* __restrict__ qo,
        _Float16* __restrict__ ko,
        _Float16* __restrict__ vo) {
    __shared__ uint4 L[8][1024];                 // 128 KiB

    const int lid = (int)blockIdx.x;             // 0..191
    const int swz = (lid & 7) * 24 + (lid >> 3); // XCD k gets 24 contiguous ids
    const int z   = swz >> 6;                    // 0..2 matrix
    const int gm  = (swz & 63) >> 3;             // 0..7 m-tile
    const int gn  = swz & 7;                     // 0..7 n-tile
    const _Float16* Wp = (z == 0) ? wq : (z == 1) ? wk : wv;
    _Float16*     Cout = (z == 0) ? qo : (z == 1) ? ko : vo;
    const int mBase = gm << 8;
    const int nBase = gn << 8;

    const int tid   = (int)threadIdx.x;
    const int lane  = tid & 63;
    const int w     = tid >> 6;
    const int l15   = lane & 15;
    const int lq    = lane >> 4;
    const int wm4   = (w >> 2) << 2;   // A row-block base (16-row units) in half-tile
    const int wn2   = (w & 3) << 1;    // B row-block base
    const int wbase = tid & 448;       // w*64 (wave-uniform LDS chunk base)

    f32x4 acc[2][2][4][2];
#pragma unroll
    for (int X = 0; X < 2; ++X)
#pragma unroll
        for (int Y = 0; Y < 2; ++Y)
#pragma unroll
            for (int mt = 0; mt < 4; ++mt)
#pragma unroll
                for (int nt = 0; nt < 2; ++nt)
                    acc[X][Y][mt][nt] = (f32x4){0.f, 0.f, 0.f, 0.f};

    half8 af[4][2], wf[2][2];

    // stage one 128x64 half-tile: linear LDS dest, per-lane global source
    // mapped so LDS chunk c=(rb,q,r) holds global (row rb*16+r, k-chunk q).
    auto stage = [&](int slot, const _Float16* src, int rowBase, int hf, int kt) {
#pragma unroll
        for (int j = 0; j < 2; ++j) {
            const int c  = (j << 9) + tid;
            const int rb = c >> 7;
            const int q  = (c >> 4) & 7;
            const int r  = c & 15;
            gl_lds16(&src[(size_t)(rowBase + hf * 128 + rb * 16 + r) * E +
                          kt * 64 + q * 8],
                     &L[slot][(j << 9) + wbase]);
        }
    };
    auto ldsA = [&](int db, int X) {         // slot = db*2+X
#pragma unroll
        for (int mt = 0; mt < 4; ++mt)
#pragma unroll
            for (int ks = 0; ks < 2; ++ks)
                af[mt][ks] = *(const half8*)&L[db * 2 + X]
                    [(wm4 + mt) * 128 + (ks * 4 + lq) * 16 + l15];
    };
    auto ldsB = [&](int db, int Y) {         // slot = 4+db*2+Y
#pragma unroll
        for (int nt = 0; nt < 2; ++nt)
#pragma unroll
            for (int ks = 0; ks < 2; ++ks)
                wf[nt][ks] = *(const half8*)&L[4 + db * 2 + Y]
                    [(wn2 + nt) * 128 + (ks * 4 + lq) * 16 + l15];
    };
    auto mma = [&](int X, int Y) {
        __builtin_amdgcn_s_setprio(1);
#pragma unroll
        for (int mt = 0; mt < 4; ++mt)
#pragma unroll
            for (int nt = 0; nt < 2; ++nt)
#pragma unroll
                for (int ks = 0; ks < 2; ++ks)
                    acc[X][Y][mt][nt] = __builtin_amdgcn_mfma_f32_16x16x32_f16(
                        af[mt][ks], wf[nt][ks], acc[X][Y][mt][nt], 0, 0, 0);
        __builtin_amdgcn_s_setprio(0);
    };

    // prologue: tile0 -> dbuf0 (all 4 halves); tile1 -> dbuf1 {A0,B1,A1}
    // (dbuf1.B0 is staged by ph0 of iter 0). Allow newest 3 stages pending.
    stage(0, hs, mBase, 0, 0);
    stage(4, Wp, nBase, 0, 0);
    stage(1, hs, mBase, 1, 0);
    stage(5, Wp, nBase, 1, 0);
    stage(2, hs, mBase, 0, 1);
    stage(7, Wp, nBase, 1, 1);
    stage(3, hs, mBase, 1, 1);
    VMW(6);
    BARX();

    for (int j = 0; j < 16; ++j) {
        const int tB  = 2 * j + 1;
        const int tN0 = 2 * j + 2;
        const int tN1 = 2 * j + 3;
        const bool more = (j < 15);

        // ph0: Q(0,0) dbuf0 | stage dbuf1.B0 <- tile 2j+1 (always valid)
        ldsA(0, 0); ldsB(0, 0);
        stage(6, Wp, nBase, 0, tB);
        BARX(); LGKM0();
        mma(0, 0);
        BARX();

        // ph1: Q(0,1) dbuf0 (reuse af X0) | stage dbuf0.A0 <- 2j+2
        ldsB(0, 1);
        if (more) stage(0, hs, mBase, 0, tN0);
        BARX(); LGKM0();
        mma(0, 1);
        BARX();

        // ph2: Q(1,1) dbuf0 (reuse wf Y1) | stage dbuf0.B1
        ldsA(0, 1);
        if (more) stage(5, Wp, nBase, 1, tN0);
        BARX(); LGKM0();
        mma(1, 1);
        BARX();

        // ph3: Q(1,0) dbuf0 (re-read B Y0) | stage dbuf0.A1 | counted vmcnt
        ldsB(0, 0);
        if (more) { stage(1, hs, mBase, 1, tN0); VMW(4); }
        else      { VMW(0); }   // last iter: ph1-4 stages skipped; ph0 must land
        BARX(); LGKM0();
        mma(1, 0);
        BARX();

        // ph4: Q(0,0) dbuf1 | stage dbuf0.B0
        ldsA(1, 0); ldsB(1, 0);
        if (more) stage(4, Wp, nBase, 0, tN0);
        BARX(); LGKM0();
        mma(0, 0);
        BARX();

        // ph5: Q(0,1) dbuf1 | stage dbuf1.A0 <- 2j+3
        ldsB(1, 1);
        if (more) stage(2, hs, mBase, 0, tN1);
        BARX(); LGKM0();
        mma(0, 1);
        BARX();

        // ph6: Q(1,1) dbuf1 | stage dbuf1.B1
        ldsA(1, 1);
        if (more) stage(7, Wp, nBase, 1, tN1);
        BARX(); LGKM0();
        mma(1, 1);
        BARX();

        // ph7: Q(1,0) dbuf1 (re-read B Y0) | stage dbuf1.A1 | counted vmcnt
        ldsB(1, 0);
        if (more) stage(3, hs, mBase, 1, tN1);
        VMW(4);
        BARX(); LGKM0();
        mma(1, 0);
        BARX();
    }

    // write (b,h,s,d) fp16
#pragma unroll
    for (int X = 0; X < 2; ++X)
#pragma unroll
        for (int Y = 0; Y < 2; ++Y)
#pragma unroll
            for (int mt = 0; mt < 4; ++mt)
#pragma unroll
                for (int nt = 0; nt < 2; ++nt)
#pragma unroll
                    for (int r = 0; r < 4; ++r) {
                        int row = mBase + X * 128 + (w >> 2) * 64 + mt * 16 + lq * 4 + r;
                        int col = nBase + Y * 128 + (w & 3) * 32 + nt * 16 + l15;
                        int b = row >> 10, s = row & (S - 1);
                        int h = col >> 7,  d = col & (HD - 1);
                        Cout[(((size_t)b * H + h) * S + s) * HD + d] =
                            (_Float16)acc[X][Y][mt][nt][r];
                    }
}

// ---------------------------------------------------------------------------
// Out-projection NT-GEMM, fp16 via global_load_lds, double-buffered, BK=32.
// Upgraded to 128x128 tile (same proven structure as the old gemm_qkv:
// 16 MFMA + 8 ds_read_b128 per wave per K-step, conflict-free [rb][kq][r]
// LDS layout). Grid 256 blocks, XCD-swizzled. fp32 C output.
// ---------------------------------------------------------------------------
__global__ __launch_bounds__(256) void gemm_out(const _Float16* __restrict__ A,
                                                const _Float16* __restrict__ Wp,
                                                float* __restrict__ C) {
    __shared__ uint4 As_l[2][512];   // 2 x 8 KB
    __shared__ uint4 Ws_l[2][512];   // 2 x 8 KB
    const int lid = (int)blockIdx.x;            // 0..255
    const int swz = (lid & 7) * 32 + (lid >> 3);
    const int gm  = swz >> 4;
    const int gn  = swz & 15;
    const int tid  = threadIdx.x;
    const int lane = tid & 63;
    const int w    = tid >> 6;
    const int wm   = (w >> 1) * 64;
    const int wn   = (w & 1) * 64;
    const int l15  = lane & 15;
    const int lq   = lane >> 4;
    const int r16  = lane & 15;
    const int kq4  = lane >> 4;
    const int mBase = gm * 128;
    const int nBase = gn * 128;

    f32x4 acc[4][4];
#pragma unroll
    for (int mt = 0; mt < 4; ++mt)
#pragma unroll
        for (int nt = 0; nt < 4; ++nt)
            acc[mt][nt] = (f32x4){0.f, 0.f, 0.f, 0.f};

    auto stage = [&](int bf, int k0) {
#pragma unroll
        for (int i = 0; i < 2; ++i) {
            int rb = w * 2 + i;
            gl_lds16(&A[(size_t)(mBase + rb * 16 + r16) * E + k0 + kq4 * 8],
                     &As_l[bf][rb * 64]);
            gl_lds16(&Wp[(size_t)(nBase + rb * 16 + r16) * E + k0 + kq4 * 8],
                     &Ws_l[bf][rb * 64]);
        }
    };

    stage(0, 0);
    const int nIter = E / 32;                   // 64
    for (int it = 0; it < nIter; ++it) {
        __syncthreads();
        if (it + 1 < nIter) stage((it + 1) & 1, (it + 1) * 32);

        const int cur = it & 1;
        half8 af[4], wfr[4];
#pragma unroll
        for (int t = 0; t < 4; ++t) {
            int rbA = (wm >> 4) + t;
            int rbW = (wn >> 4) + t;
            af[t]  = *(const half8*)&As_l[cur][rbA * 64 + lq * 16 + l15];
            wfr[t] = *(const half8*)&Ws_l[cur][rbW * 64 + lq * 16 + l15];
        }
#pragma unroll
        for (int mt = 0; mt < 4; ++mt)
#pragma unroll
            for (int nt = 0; nt < 4; ++nt)
                acc[mt][nt] = __builtin_amdgcn_mfma_f32_16x16x32_f16(
                    af[mt], wfr[nt], acc[mt][nt], 0, 0, 0);
    }

#pragma unroll
    for (int mt = 0; mt < 4; ++mt)
#pragma unroll
        for (int nt = 0; nt < 4; ++nt)
#pragma unroll
            for (int r = 0; r < 4; ++r) {
                int row = mBase + wm + mt * 16 + lq * 4 + r;
                int col = nBase + wn + nt * 16 + l15;
                C[(size_t)row * E + col] = acc[mt][nt][r];
            }
}

// ---------------------------------------------------------------------------
// Rotary + L2 normalize + mask, in-place on fp16 (b,h,s,d).
// ---------------------------------------------------------------------------
__global__ __launch_bounds__(256) void rotary_norm(_Float16* __restrict__ qh,
                                                   _Float16* __restrict__ kh,
                                                   const float* __restrict__ am,
                                                   const int* __restrict__ pos) {
    const int wave = threadIdx.x >> 6;
    const int lane = threadIdx.x & 63;
    const int item = blockIdx.x * 4 + wave;      // < B*H*S
    const int b = item / (H * S);
    const int h = (item / S) % H;
    const int s = item % S;

    const float p = (float)pos[b * S + s];
    float co = 1.f, si = 0.f;
    if (lane < 32) {
        float ang = p * expf(-0.28782313662425574f * (float)lane); // ln(10000)/32
        sincosf(ang, &si, &co);
    }
    const float valid = (am[b * S + s] == 0.f) ? 1.f : 0.f;
    const size_t base = ((size_t)(b * H + h) * S + s) * HD;

    _Float16* bufs[2] = {qh, kh};
#pragma unroll
    for (int a = 0; a < 2; ++a) {
        _Float16* ptr = bufs[a];
        half2 xin = *(const half2*)&ptr[base + 2 * lane];
        float x0 = (float)xin[0], x1 = (float)xin[1];
        float y0, y1;
        if (lane < 32) {
            y0 = x0 * co - x1 * si;
            y1 = x1 * co + x0 * si;
        } else {
            y0 = x0;
            y1 = x1;
        }
        float ss = y0 * y0 + y1 * y1;
#pragma unroll
        for (int off = 32; off > 0; off >>= 1)
            ss += __shfl_xor(ss, off);
        float scale = valid / fmaxf(sqrtf(ss), EPSN);
        half2 xo;
        xo[0] = (_Float16)(y0 * scale);
        xo[1] = (_Float16)(y1 * scale);
        *(half2*)&ptr[base + 2 * lane] = xo;
    }
}

// ---------------------------------------------------------------------------
// vprep: v (b,h,s,d) fp16 -> scaled V^T (b,h,d,s) fp16,
// scale = mask / max(counts^sigmoid(nc[h]), 1), counts via in-block wave scan.
// ---------------------------------------------------------------------------
__global__ __launch_bounds__(256) void vprep(const _Float16* __restrict__ v,
                                             _Float16* __restrict__ vt,
                                             const float* __restrict__ am,
                                             const float* __restrict__ nc) {
    __shared__ _Float16 T[HD][72];     // [d][s] pad 8
    __shared__ float sscale[64];
    const int bh = blockIdx.y;
    const int b = bh >> 4, h = bh & 15;
    const int s0 = blockIdx.x * 64;
    const int tid = threadIdx.x;

    if (tid < 64) {
        const int lane = tid;
        float basec = 0.f;
        for (int j0 = 0; j0 < s0; j0 += 64) {
            float z = (am[b * S + j0 + lane] == 0.f) ? 1.f : 0.f;
#pragma unroll
            for (int off = 32; off > 0; off >>= 1)
                z += __shfl_xor(z, off);
            basec += z;
        }
        float zown = (am[b * S + s0 + lane] == 0.f) ? 1.f : 0.f;
        float sc = zown;
#pragma unroll
        for (int off = 1; off < 64; off <<= 1) {
            float u = __shfl_up(sc, off);
            if (lane >= off) sc += u;
        }
        float cntv = basec + sc;
        float sig = 1.f / (1.f + expf(-nc[h]));
        float denom = fmaxf(powf(cntv, sig), 1.f);
        sscale[lane] = zown / denom;
    }
    __syncthreads();

#pragma unroll
    for (int j = 0; j < 4; ++j) {
        int f = tid + j * 256;
        int s = f >> 4, c8 = f & 15;
        half8 x = *(const half8*)&v[((size_t)bh * S + s0 + s) * HD + c8 * 8];
        float sc = sscale[s];
#pragma unroll
        for (int i = 0; i < 8; ++i)
            T[c8 * 8 + i][s] = (_Float16)((float)x[i] * sc);
    }
    __syncthreads();

#pragma unroll
    for (int j = 0; j < 4; ++j) {
        int f = tid + j * 256;
        int d = f >> 3, c8 = f & 7;
        *(uint4*)&vt[((size_t)bh * HD + d) * S + s0 + c8 * 8] =
            *(const uint4*)&T[d][c8 * 8];
    }
}

// ---------------------------------------------------------------------------
// MFMA attention with register prefetch of the next K/V chunk.
// qh,kh: (b,h,s,d); vt: (b,h,d,s); o: (b,s,E) fp16.
// ---------------------------------------------------------------------------
__global__ __launch_bounds__(256) void attn_mfma(const _Float16* __restrict__ qh,
                                                 const _Float16* __restrict__ kh,
                                                 const _Float16* __restrict__ vt,
                                                 _Float16* __restrict__ o) {
    __shared__ _Float16 Ks[64][136];   // [key][d], +8 pad
    __shared__ _Float16 Vs[HD][72];    // [d][key], +8 pad
    __shared__ _Float16 Ps[64][72];    // [q][key], +8 pad

    const int qt = (int)gridDim.x - 1 - (int)blockIdx.x;   // heavy first
    const int bh = blockIdx.y;
    const int b = bh >> 4, h = bh & 15;
    const int tid = threadIdx.x;
    const int lane = tid & 63;
    const int w = tid >> 6;
    const int l15 = lane & 15;
    const int lq = lane >> 4;
    const int qBase = qt * 64;
    const size_t sd_base = (size_t)bh * S * HD;

    half8 qf[4];
#pragma unroll
    for (int ks = 0; ks < 4; ++ks)
        qf[ks] = *(const half8*)&qh[sd_base + (size_t)(qBase + w * 16 + l15) * HD +
                                    ks * 32 + lq * 8];

    f32x4 oacc[8];
#pragma unroll
    for (int dt = 0; dt < 8; ++dt)
        oacc[dt] = (f32x4){0.f, 0.f, 0.f, 0.f};

    const int nkc = qt + 1;
    uint4 pk[4], pv[4];
#pragma unroll
    for (int j = 0; j < 4; ++j) {
        int f = tid + j * 256;
        int rK = f >> 4, c8K = f & 15;
        int rV = f >> 3, c8V = f & 7;
        pk[j] = *(const uint4*)&kh[sd_base + (size_t)rK * HD + c8K * 8];
        pv[j] = *(const uint4*)&vt[sd_base + (size_t)rV * S + c8V * 8];
    }

    for (int kc = 0; kc < nkc; ++kc) {
        __syncthreads();
#pragma unroll
        for (int j = 0; j < 4; ++j) {
            int f = tid + j * 256;
            int rK = f >> 4, c8K = f & 15;
            int rV = f >> 3, c8V = f & 7;
            *(uint4*)&Ks[rK][c8K * 8] = pk[j];
            *(uint4*)&Vs[rV][c8V * 8] = pv[j];
        }
        __syncthreads();

        if (kc + 1 < nkc) {
            const int kB = (kc + 1) * 64;
#pragma unroll
            for (int j = 0; j < 4; ++j) {
                int f = tid + j * 256;
                int rK = f >> 4, c8K = f & 15;
                int rV = f >> 3, c8V = f & 7;
                pk[j] = *(const uint4*)&kh[sd_base + (size_t)(kB + rK) * HD + c8K * 8];
                pv[j] = *(const uint4*)&vt[sd_base + (size_t)rV * S + kB + c8V * 8];
            }
        }

        const int kBase = kc * 64;
        f32x4 sacc[4];
#pragma unroll
        for (int nt = 0; nt < 4; ++nt)
            sacc[nt] = (f32x4){0.f, 0.f, 0.f, 0.f};
#pragma unroll
        for (int nt = 0; nt < 4; ++nt)
#pragma unroll
            for (int ks = 0; ks < 4; ++ks) {
                half8 kf = *(const half8*)&Ks[nt * 16 + l15][ks * 32 + lq * 8];
                sacc[nt] = __builtin_amdgcn_mfma_f32_16x16x32_f16(qf[ks], kf,
                                                                  sacc[nt], 0, 0, 0);
            }

#pragma unroll
        for (int nt = 0; nt < 4; ++nt)
#pragma unroll
            for (int r = 0; r < 4; ++r) {
                int qg = qBase + w * 16 + lq * 4 + r;
                int kg = kBase + nt * 16 + l15;
                float sv = (kg <= qg) ? sacc[nt][r] : 0.f;
                Ps[w * 16 + lq * 4 + r][nt * 16 + l15] = (_Float16)sv;
            }

        half8 pf[2];
        pf[0] = *(const half8*)&Ps[w * 16 + l15][lq * 8];
        pf[1] = *(const half8*)&Ps[w * 16 + l15][32 + lq * 8];
#pragma unroll
        for (int dt = 0; dt < 8; ++dt)
#pragma unroll
            for (int ks = 0; ks < 2; ++ks) {
                half8 vf = *(const half8*)&Vs[dt * 16 + l15][ks * 32 + lq * 8];
                oacc[dt] = __builtin_amdgcn_mfma_f32_16x16x32_f16(pf[ks], vf,
                                                                  oacc[dt], 0, 0, 0);
            }
    }

#pragma unroll
    for (int dt = 0; dt < 8; ++dt)
#pragma unroll
        for (int r = 0; r < 4; ++r) {
            size_t off = (size_t)(b * S + qBase + w * 16 + lq * 4 + r) * E +
                         h * HD + dt * 16 + l15;
            o[off] = (_Float16)oacc[dt][r];
        }
}

// ---------------------------------------------------------------------------
extern "C" void kernel_launch(void* const* d_in, const int* in_sizes, int n_in,
                              void* d_out, int out_size, void* d_ws, size_t ws_size,
                              hipStream_t stream) {
    (void)in_sizes; (void)n_in; (void)out_size; (void)ws_size;
    const float* hs = (const float*)d_in[0];
    const float* wq = (const float*)d_in[1];
    const float* wk = (const float*)d_in[2];
    const float* wv = (const float*)d_in[3];
    const float* wo = (const float*)d_in[4];
    const float* nc = (const float*)d_in[5];
    const float* am = (const float*)d_in[6];
    const int*  pos = (const int*)d_in[7];
    float* out = (float*)d_out;

    const size_t act = (size_t)B * S * E;           // 4,194,304 (== E*E)
    _Float16* hsb = (_Float16*)d_ws;                // fp16 copies
    _Float16* wqb = hsb + act;
    _Float16* wkb = wqb + act;
    _Float16* wvb = wkb + act;
    _Float16* wob = wvb + act;
    _Float16* qhh = wob + act;                      // (b,h,s,d)
    _Float16* khh = qhh + act;
    _Float16* vhh = khh + act;                      // (b,h,s,d)
    _Float16* vtt = vhh + act;                      // (b,h,d,s)
    _Float16* abb = vtt + act;                      // attn out (b,s,E)
    // total ws: 10 * 8.39MB ~= 84 MB

    f2h5<<<dim3((int)(act / 4 / 256), 5), 256, 0, stream>>>(
        hs, wq, wk, wv, wo, hsb, wqb, wkb, wvb, wob);

    gemm_qkv256<<<192, 512, 0, stream>>>(hsb, wqb, wkb, wvb, qhh, khh, vhh);

    rotary_norm<<<(B * H * S) / 4, 256, 0, stream>>>(qhh, khh, am, pos);
    vprep<<<dim3(S / 64, B * H), 256, 0, stream>>>(vhh, vtt, am, nc);

    attn_mfma<<<dim3(S / 64, B * H), 256, 0, stream>>>(qhh, khh, vtt, abb);

    gemm_out<<<256, 256, 0, stream>>>(abb, wob, out);
}

// Round 2
// 301.419 us; speedup vs baseline: 1.2837x; 1.1854x over previous
//
#include <hip/hip_runtime.h>
#include <math.h>

#define B 2
#define S 1024
#define E 2048
#define H 16
#define HD 128
#define ROT 64
#define EPSN 1e-12f

using half8 = __attribute__((ext_vector_type(8))) _Float16;
using half4 = __attribute__((ext_vector_type(4))) _Float16;
using half2 = __attribute__((ext_vector_type(2))) _Float16;
using f32x4 = __attribute__((ext_vector_type(4))) float;

// async global->LDS, 16B per lane; LDS dest = wave-uniform base + lane*16
__device__ __forceinline__ void gl_lds16(const void* g, void* l) {
    __builtin_amdgcn_global_load_lds(
        (const __attribute__((address_space(1))) unsigned int*)g,
        (__attribute__((address_space(3))) unsigned int*)l, 16, 0, 0);
}

#define BARX()  asm volatile("s_barrier" ::: "memory")
#define LGKM0() asm volatile("s_waitcnt lgkmcnt(0)" ::: "memory")
#define VMW(n)  asm volatile("s_waitcnt vmcnt(" #n ")" ::: "memory")

// ---------------------------------------------------------------------------
// Batched fp32 -> fp16: 5 tensors, each exactly B*S*E = E*E = 4M elements.
// ---------------------------------------------------------------------------
__global__ __launch_bounds__(256) void f2h5(const float* __restrict__ x0,
                                            const float* __restrict__ x1,
                                            const float* __restrict__ x2,
                                            const float* __restrict__ x3,
                                            const float* __restrict__ x4,
                                            _Float16* __restrict__ y0,
                                            _Float16* __restrict__ y1,
                                            _Float16* __restrict__ y2,
                                            _Float16* __restrict__ y3,
                                            _Float16* __restrict__ y4) {
    const float* xs[5] = {x0, x1, x2, x3, x4};
    _Float16*    ys[5] = {y0, y1, y2, y3, y4};
    const int t = blockIdx.y;
    const int i = blockIdx.x * 256 + threadIdx.x;
    float4 v = ((const float4*)xs[t])[i];
    half4 h;
    h[0] = (_Float16)v.x; h[1] = (_Float16)v.y;
    h[2] = (_Float16)v.z; h[3] = (_Float16)v.w;
    ((half4*)ys[t])[i] = h;
}

// ---------------------------------------------------------------------------
// Fused QKV NT-GEMM, 256x256 tile, BK=64, 8-phase pipelined schedule.
// (unchanged from previous round — verified win)
// ---------------------------------------------------------------------------
__global__ __launch_bounds__(512, 2) void gemm_qkv256(
        const _Float16* __restrict__ hs,
        const _Float16* __restrict__ wq,
        const _Float16* __restrict__ wk,
        const _Float16* __restrict__ wv,
        _Float16* __restrict__ qo,
        _Float16* __restrict__ ko,
        _Float16* __restrict__ vo) {
    __shared__ uint4 L[8][1024];                 // 128 KiB

    const int lid = (int)blockIdx.x;             // 0..191
    const int swz = (lid & 7) * 24 + (lid >> 3); // XCD k gets 24 contiguous ids
    const int z   = swz >> 6;                    // 0..2 matrix
    const int gm  = (swz & 63) >> 3;             // 0..7 m-tile
    const int gn  = swz & 7;                     // 0..7 n-tile
    const _Float16* Wp = (z == 0) ? wq : (z == 1) ? wk : wv;
    _Float16*     Cout = (z == 0) ? qo : (z == 1) ? ko : vo;
    const int mBase = gm << 8;
    const int nBase = gn << 8;

    const int tid   = (int)threadIdx.x;
    const int lane  = tid & 63;
    const int w     = tid >> 6;
    const int l15   = lane & 15;
    const int lq    = lane >> 4;
    const int wm4   = (w >> 2) << 2;
    const int wn2   = (w & 3) << 1;
    const int wbase = tid & 448;

    f32x4 acc[2][2][4][2];
#pragma unroll
    for (int X = 0; X < 2; ++X)
#pragma unroll
        for (int Y = 0; Y < 2; ++Y)
#pragma unroll
            for (int mt = 0; mt < 4; ++mt)
#pragma unroll
                for (int nt = 0; nt < 2; ++nt)
                    acc[X][Y][mt][nt] = (f32x4){0.f, 0.f, 0.f, 0.f};

    half8 af[4][2], wf[2][2];

    auto stage = [&](int slot, const _Float16* src, int rowBase, int hf, int kt) {
#pragma unroll
        for (int j = 0; j < 2; ++j) {
            const int c  = (j << 9) + tid;
            const int rb = c >> 7;
            const int q  = (c >> 4) & 7;
            const int r  = c & 15;
            gl_lds16(&src[(size_t)(rowBase + hf * 128 + rb * 16 + r) * E +
                          kt * 64 + q * 8],
                     &L[slot][(j << 9) + wbase]);
        }
    };
    auto ldsA = [&](int db, int X) {
#pragma unroll
        for (int mt = 0; mt < 4; ++mt)
#pragma unroll
            for (int ks = 0; ks < 2; ++ks)
                af[mt][ks] = *(const half8*)&L[db * 2 + X]
                    [(wm4 + mt) * 128 + (ks * 4 + lq) * 16 + l15];
    };
    auto ldsB = [&](int db, int Y) {
#pragma unroll
        for (int nt = 0; nt < 2; ++nt)
#pragma unroll
            for (int ks = 0; ks < 2; ++ks)
                wf[nt][ks] = *(const half8*)&L[4 + db * 2 + Y]
                    [(wn2 + nt) * 128 + (ks * 4 + lq) * 16 + l15];
    };
    auto mma = [&](int X, int Y) {
        __builtin_amdgcn_s_setprio(1);
#pragma unroll
        for (int mt = 0; mt < 4; ++mt)
#pragma unroll
            for (int nt = 0; nt < 2; ++nt)
#pragma unroll
                for (int ks = 0; ks < 2; ++ks)
                    acc[X][Y][mt][nt] = __builtin_amdgcn_mfma_f32_16x16x32_f16(
                        af[mt][ks], wf[nt][ks], acc[X][Y][mt][nt], 0, 0, 0);
        __builtin_amdgcn_s_setprio(0);
    };

    stage(0, hs, mBase, 0, 0);
    stage(4, Wp, nBase, 0, 0);
    stage(1, hs, mBase, 1, 0);
    stage(5, Wp, nBase, 1, 0);
    stage(2, hs, mBase, 0, 1);
    stage(7, Wp, nBase, 1, 1);
    stage(3, hs, mBase, 1, 1);
    VMW(6);
    BARX();

    for (int j = 0; j < 16; ++j) {
        const int tB  = 2 * j + 1;
        const int tN0 = 2 * j + 2;
        const int tN1 = 2 * j + 3;
        const bool more = (j < 15);

        ldsA(0, 0); ldsB(0, 0);
        stage(6, Wp, nBase, 0, tB);
        BARX(); LGKM0();
        mma(0, 0);
        BARX();

        ldsB(0, 1);
        if (more) stage(0, hs, mBase, 0, tN0);
        BARX(); LGKM0();
        mma(0, 1);
        BARX();

        ldsA(0, 1);
        if (more) stage(5, Wp, nBase, 1, tN0);
        BARX(); LGKM0();
        mma(1, 1);
        BARX();

        ldsB(0, 0);
        if (more) { stage(1, hs, mBase, 1, tN0); VMW(4); }
        else      { VMW(0); }
        BARX(); LGKM0();
        mma(1, 0);
        BARX();

        ldsA(1, 0); ldsB(1, 0);
        if (more) stage(4, Wp, nBase, 0, tN0);
        BARX(); LGKM0();
        mma(0, 0);
        BARX();

        ldsB(1, 1);
        if (more) stage(2, hs, mBase, 0, tN1);
        BARX(); LGKM0();
        mma(0, 1);
        BARX();

        ldsA(1, 1);
        if (more) stage(7, Wp, nBase, 1, tN1);
        BARX(); LGKM0();
        mma(1, 1);
        BARX();

        ldsB(1, 0);
        if (more) stage(3, hs, mBase, 1, tN1);
        VMW(4);
        BARX(); LGKM0();
        mma(1, 0);
        BARX();
    }

#pragma unroll
    for (int X = 0; X < 2; ++X)
#pragma unroll
        for (int Y = 0; Y < 2; ++Y)
#pragma unroll
            for (int mt = 0; mt < 4; ++mt)
#pragma unroll
                for (int nt = 0; nt < 2; ++nt)
#pragma unroll
                    for (int r = 0; r < 4; ++r) {
                        int row = mBase + X * 128 + (w >> 2) * 64 + mt * 16 + lq * 4 + r;
                        int col = nBase + Y * 128 + (w & 3) * 32 + nt * 16 + l15;
                        int b = row >> 10, s = row & (S - 1);
                        int h = col >> 7,  d = col & (HD - 1);
                        Cout[(((size_t)b * H + h) * S + s) * HD + d] =
                            (_Float16)acc[X][Y][mt][nt][r];
                    }
}

// ---------------------------------------------------------------------------
// Out-projection NT-GEMM, 128x128, double-buffered, BK=32 (unchanged).
// ---------------------------------------------------------------------------
__global__ __launch_bounds__(256) void gemm_out(const _Float16* __restrict__ A,
                                                const _Float16* __restrict__ Wp,
                                                float* __restrict__ C) {
    __shared__ uint4 As_l[2][512];
    __shared__ uint4 Ws_l[2][512];
    const int lid = (int)blockIdx.x;
    const int swz = (lid & 7) * 32 + (lid >> 3);
    const int gm  = swz >> 4;
    const int gn  = swz & 15;
    const int tid  = threadIdx.x;
    const int lane = tid & 63;
    const int w    = tid >> 6;
    const int wm   = (w >> 1) * 64;
    const int wn   = (w & 1) * 64;
    const int l15  = lane & 15;
    const int lq   = lane >> 4;
    const int r16  = lane & 15;
    const int kq4  = lane >> 4;
    const int mBase = gm * 128;
    const int nBase = gn * 128;

    f32x4 acc[4][4];
#pragma unroll
    for (int mt = 0; mt < 4; ++mt)
#pragma unroll
        for (int nt = 0; nt < 4; ++nt)
            acc[mt][nt] = (f32x4){0.f, 0.f, 0.f, 0.f};

    auto stage = [&](int bf, int k0) {
#pragma unroll
        for (int i = 0; i < 2; ++i) {
            int rb = w * 2 + i;
            gl_lds16(&A[(size_t)(mBase + rb * 16 + r16) * E + k0 + kq4 * 8],
                     &As_l[bf][rb * 64]);
            gl_lds16(&Wp[(size_t)(nBase + rb * 16 + r16) * E + k0 + kq4 * 8],
                     &Ws_l[bf][rb * 64]);
        }
    };

    stage(0, 0);
    const int nIter = E / 32;
    for (int it = 0; it < nIter; ++it) {
        __syncthreads();
        if (it + 1 < nIter) stage((it + 1) & 1, (it + 1) * 32);

        const int cur = it & 1;
        half8 af[4], wfr[4];
#pragma unroll
        for (int t = 0; t < 4; ++t) {
            int rbA = (wm >> 4) + t;
            int rbW = (wn >> 4) + t;
            af[t]  = *(const half8*)&As_l[cur][rbA * 64 + lq * 16 + l15];
            wfr[t] = *(const half8*)&Ws_l[cur][rbW * 64 + lq * 16 + l15];
        }
#pragma unroll
        for (int mt = 0; mt < 4; ++mt)
#pragma unroll
            for (int nt = 0; nt < 4; ++nt)
                acc[mt][nt] = __builtin_amdgcn_mfma_f32_16x16x32_f16(
                    af[mt], wfr[nt], acc[mt][nt], 0, 0, 0);
    }

#pragma unroll
    for (int mt = 0; mt < 4; ++mt)
#pragma unroll
        for (int nt = 0; nt < 4; ++nt)
#pragma unroll
            for (int r = 0; r < 4; ++r) {
                int row = mBase + wm + mt * 16 + lq * 4 + r;
                int col = nBase + wn + nt * 16 + l15;
                C[(size_t)row * E + col] = acc[mt][nt][r];
            }
}

// ---------------------------------------------------------------------------
// Rotary + L2 normalize + mask, in-place on fp16 (b,h,s,d). (unchanged)
// ---------------------------------------------------------------------------
__global__ __launch_bounds__(256) void rotary_norm(_Float16* __restrict__ qh,
                                                   _Float16* __restrict__ kh,
                                                   const float* __restrict__ am,
                                                   const int* __restrict__ pos) {
    const int wave = threadIdx.x >> 6;
    const int lane = threadIdx.x & 63;
    const int item = blockIdx.x * 4 + wave;
    const int b = item / (H * S);
    const int h = (item / S) % H;
    const int s = item % S;

    const float p = (float)pos[b * S + s];
    float co = 1.f, si = 0.f;
    if (lane < 32) {
        float ang = p * expf(-0.28782313662425574f * (float)lane);
        sincosf(ang, &si, &co);
    }
    const float valid = (am[b * S + s] == 0.f) ? 1.f : 0.f;
    const size_t base = ((size_t)(b * H + h) * S + s) * HD;

    _Float16* bufs[2] = {qh, kh};
#pragma unroll
    for (int a = 0; a < 2; ++a) {
        _Float16* ptr = bufs[a];
        half2 xin = *(const half2*)&ptr[base + 2 * lane];
        float x0 = (float)xin[0], x1 = (float)xin[1];
        float y0, y1;
        if (lane < 32) {
            y0 = x0 * co - x1 * si;
            y1 = x1 * co + x0 * si;
        } else {
            y0 = x0;
            y1 = x1;
        }
        float ss = y0 * y0 + y1 * y1;
#pragma unroll
        for (int off = 32; off > 0; off >>= 1)
            ss += __shfl_xor(ss, off);
        float scale = valid / fmaxf(sqrtf(ss), EPSN);
        half2 xo;
        xo[0] = (_Float16)(y0 * scale);
        xo[1] = (_Float16)(y1 * scale);
        *(half2*)&ptr[base + 2 * lane] = xo;
    }
}

// ---------------------------------------------------------------------------
// vprep: v (b,h,s,d) -> scaled V^T (b,h,d,s), AND k (b,h,s,d) -> K^T (b,h,d,s)
// via the same LDS transpose (K already masked/normalized by rotary_norm).
// ---------------------------------------------------------------------------
__global__ __launch_bounds__(256) void vprep(const _Float16* __restrict__ v,
                                             const _Float16* __restrict__ k,
                                             _Float16* __restrict__ vt,
                                             _Float16* __restrict__ kt,
                                             const float* __restrict__ am,
                                             const float* __restrict__ nc) {
    __shared__ _Float16 T[HD][72];     // [d][s] pad 8
    __shared__ float sscale[64];
    const int bh = blockIdx.y;
    const int b = bh >> 4, h = bh & 15;
    const int s0 = blockIdx.x * 64;
    const int tid = threadIdx.x;

    if (tid < 64) {
        const int lane = tid;
        float basec = 0.f;
        for (int j0 = 0; j0 < s0; j0 += 64) {
            float z = (am[b * S + j0 + lane] == 0.f) ? 1.f : 0.f;
#pragma unroll
            for (int off = 32; off > 0; off >>= 1)
                z += __shfl_xor(z, off);
            basec += z;
        }
        float zown = (am[b * S + s0 + lane] == 0.f) ? 1.f : 0.f;
        float sc = zown;
#pragma unroll
        for (int off = 1; off < 64; off <<= 1) {
            float u = __shfl_up(sc, off);
            if (lane >= off) sc += u;
        }
        float cntv = basec + sc;
        float sig = 1.f / (1.f + expf(-nc[h]));
        float denom = fmaxf(powf(cntv, sig), 1.f);
        sscale[lane] = zown / denom;
    }
    __syncthreads();

    // V: scale + transpose
#pragma unroll
    for (int j = 0; j < 4; ++j) {
        int f = tid + j * 256;
        int s = f >> 4, c8 = f & 15;
        half8 x = *(const half8*)&v[((size_t)bh * S + s0 + s) * HD + c8 * 8];
        float sc = sscale[s];
#pragma unroll
        for (int i = 0; i < 8; ++i)
            T[c8 * 8 + i][s] = (_Float16)((float)x[i] * sc);
    }
    __syncthreads();
#pragma unroll
    for (int j = 0; j < 4; ++j) {
        int f = tid + j * 256;
        int d = f >> 3, c8 = f & 7;
        *(uint4*)&vt[((size_t)bh * HD + d) * S + s0 + c8 * 8] =
            *(const uint4*)&T[d][c8 * 8];
    }

    // K: transpose only
    __syncthreads();
#pragma unroll
    for (int j = 0; j < 4; ++j) {
        int f = tid + j * 256;
        int s = f >> 4, c8 = f & 15;
        half8 x = *(const half8*)&k[((size_t)bh * S + s0 + s) * HD + c8 * 8];
#pragma unroll
        for (int i = 0; i < 8; ++i)
            T[c8 * 8 + i][s] = x[i];
    }
    __syncthreads();
#pragma unroll
    for (int j = 0; j < 4; ++j) {
        int f = tid + j * 256;
        int d = f >> 3, c8 = f & 7;
        *(uint4*)&kt[((size_t)bh * HD + d) * S + s0 + c8 * 8] =
            *(const uint4*)&T[d][c8 * 8];
    }
}

// ---------------------------------------------------------------------------
// kvouter: U_c = K_c^T V_c (128x128, contract 64) per (bh, chunk c).
// Inputs Kt, Vt in (b,h,d,s). Output Ut fp16 in FRAGMENT-MAJOR M^T layout:
// flat = ((dt*4+ks)*64 + lane')*8 + j holds Mt[dv=dt*16+(lane'&15)]
// [dk=ks*32+(lane'>>4)*8+j]  -> consumer does linear gl_lds16 + conflict-free
// ds_read_b128 frag loads. LDS-bounce transpose for coalesced global stores.
// ---------------------------------------------------------------------------
__global__ __launch_bounds__(256) void kvouter(const _Float16* __restrict__ kt,
                                               const _Float16* __restrict__ vt,
                                               _Float16* __restrict__ ut) {
    __shared__ __align__(16) _Float16 SB[2 * 128 * 72];   // 36 KB
    _Float16 (*Kt_s)[72] = (_Float16(*)[72])SB;
    _Float16 (*Vt_s)[72] = (_Float16(*)[72])(SB + 128 * 72);
    const int c  = blockIdx.x;        // chunk 0..15
    const int bh = blockIdx.y;
    const int tid = threadIdx.x;
    const int lane = tid & 63, w = tid >> 6;
    const int l15 = lane & 15, lq = lane >> 4;
    const size_t ds_b = (size_t)bh * HD * S + (size_t)c * 64;

    uint4 pk[4], pv[4];
#pragma unroll
    for (int j = 0; j < 4; ++j) {
        int f = tid + j * 256;
        int d = f >> 3, c8 = f & 7;
        pk[j] = *(const uint4*)&kt[ds_b + (size_t)d * S + c8 * 8];
        pv[j] = *(const uint4*)&vt[ds_b + (size_t)d * S + c8 * 8];
    }
#pragma unroll
    for (int j = 0; j < 4; ++j) {
        int f = tid + j * 256;
        int d = f >> 3, c8 = f & 7;
        *(uint4*)&Kt_s[d][c8 * 8] = pk[j];
        *(uint4*)&Vt_s[d][c8 * 8] = pv[j];
    }
    __syncthreads();

    f32x4 acc[2][8];
#pragma unroll
    for (int mt = 0; mt < 2; ++mt)
#pragma unroll
        for (int nt = 0; nt < 8; ++nt)
            acc[mt][nt] = (f32x4){0.f, 0.f, 0.f, 0.f};

#pragma unroll
    for (int ks = 0; ks < 2; ++ks) {
        half8 af[2], wf[8];
#pragma unroll
        for (int mt = 0; mt < 2; ++mt)
            af[mt] = *(const half8*)&Kt_s[(w * 2 + mt) * 16 + l15][ks * 32 + lq * 8];
#pragma unroll
        for (int nt = 0; nt < 8; ++nt)
            wf[nt] = *(const half8*)&Vt_s[nt * 16 + l15][ks * 32 + lq * 8];
#pragma unroll
        for (int mt = 0; mt < 2; ++mt)
#pragma unroll
            for (int nt = 0; nt < 8; ++nt)
                acc[mt][nt] = __builtin_amdgcn_mfma_f32_16x16x32_f16(
                    af[mt], wf[nt], acc[mt][nt], 0, 0, 0);
    }
    __syncthreads();                      // all frag reads done -> overlay Mb

    _Float16* Mb = SB;                    // 16384 halves, fits in SB
#pragma unroll
    for (int mt = 0; mt < 2; ++mt)
#pragma unroll
        for (int nt = 0; nt < 8; ++nt)
#pragma unroll
            for (int r = 0; r < 4; ++r) {
                int dk = (w * 2 + mt) * 16 + lq * 4 + r;   // C row
                // dv = nt*16 + l15 (C col); frag-major flat index:
                int flat = nt * 2048 + (dk >> 5) * 512 +
                           (l15 + ((dk >> 3) & 3) * 16) * 8 + (dk & 7);
                Mb[flat] = (_Float16)acc[mt][nt][r];
            }
    __syncthreads();

    const size_t ub = ((size_t)bh * 16 + c) << 14;
#pragma unroll
    for (int j = 0; j < 8; ++j) {
        int f = tid + j * 256;
        *(uint4*)&ut[ub + (size_t)f * 8] = *(const uint4*)&Mb[f * 8];
    }
}

// ---------------------------------------------------------------------------
// prefix16: in-place EXCLUSIVE prefix sum over the 16 chunk matrices per bh.
// Ut[bh][c] <- sum_{c'<c} Ut[bh][c'] (fp32 accumulate, fp16 store).
// Grid: 32 bh x 8 slices of 2048 elems; each thread owns one half8.
// ---------------------------------------------------------------------------
__global__ __launch_bounds__(256) void prefix16(_Float16* __restrict__ u) {
    const int sl = blockIdx.x & 7;
    const int bh = blockIdx.x >> 3;
    const size_t base = (size_t)bh * 16 * 16384 + sl * 2048 + threadIdx.x * 8;
    float acc[8] = {0.f, 0.f, 0.f, 0.f, 0.f, 0.f, 0.f, 0.f};
    half8 nxt = *(const half8*)&u[base];
#pragma unroll
    for (int c = 0; c < 16; ++c) {
        half8 cur = nxt;
        if (c < 15) nxt = *(const half8*)&u[base + (size_t)(c + 1) * 16384];
        half8 outv;
#pragma unroll
        for (int i = 0; i < 8; ++i) outv[i] = (_Float16)acc[i];
        *(half8*)&u[base + (size_t)c * 16384] = outv;
#pragma unroll
        for (int i = 0; i < 8; ++i) acc[i] += (float)cur[i];
    }
}

// ---------------------------------------------------------------------------
// attn_local: uniform one-shot blocks (bh, qt).
// O_tile = Q_tile · M^T_qt  +  tril(Q_tile K_qt^T) V_qt.
// M^T staged via linear gl_lds16 (frag-major layout from kvouter/prefix16).
// Coalesced O epilogue via LDS bounce (Ob overlays Ks).
// ---------------------------------------------------------------------------
__global__ __launch_bounds__(256) void attn_local(const _Float16* __restrict__ qh,
                                                  const _Float16* __restrict__ kh,
                                                  const _Float16* __restrict__ vt,
                                                  const _Float16* __restrict__ mt,
                                                  _Float16* __restrict__ o) {
    __shared__ _Float16 Ks[64][136];   // [key][d], +8 pad (overlaid by Ob later)
    __shared__ _Float16 Vs[HD][72];    // [d][key], +8 pad
    __shared__ _Float16 Ps[64][72];    // [q][key], +8 pad
    __shared__ uint4 Ms[2048];         // 32 KB frag-major M^T (linear)

    const int qt = blockIdx.x;
    const int bh = blockIdx.y;
    const int b = bh >> 4, h = bh & 15;
    const int tid = threadIdx.x;
    const int lane = tid & 63;
    const int w = tid >> 6;
    const int l15 = lane & 15;
    const int lq = lane >> 4;
    const int qBase = qt * 64;
    const size_t sd_base = (size_t)bh * S * HD;

    // Q A-frags (registers)
    half8 qf[4];
#pragma unroll
    for (int ks = 0; ks < 4; ++ks)
        qf[ks] = *(const half8*)&qh[sd_base + (size_t)(qBase + w * 16 + l15) * HD +
                                    ks * 32 + lq * 8];

    // M^T staging: 8 x (4 waves x 1 KB) = 32 KB, linear
    const _Float16* mtc = mt + (((size_t)bh * 16 + qt) << 14);
#pragma unroll
    for (int rr = 0; rr < 8; ++rr)
        gl_lds16(&mtc[(size_t)((rr * 4 + w) * 64 + lane) * 8],
                 &Ms[(rr * 4 + w) * 64]);

    // local K, V^T chunk -> regs -> LDS
    uint4 pk[4], pv[4];
#pragma unroll
    for (int j = 0; j < 4; ++j) {
        int f = tid + j * 256;
        int rK = f >> 4, c8K = f & 15;
        int rV = f >> 3, c8V = f & 7;
        pk[j] = *(const uint4*)&kh[sd_base + (size_t)(qBase + rK) * HD + c8K * 8];
        pv[j] = *(const uint4*)&vt[sd_base + (size_t)rV * S + qBase + c8V * 8];
    }
#pragma unroll
    for (int j = 0; j < 4; ++j) {
        int f = tid + j * 256;
        int rK = f >> 4, c8K = f & 15;
        int rV = f >> 3, c8V = f & 7;
        *(uint4*)&Ks[rK][c8K * 8] = pk[j];
        *(uint4*)&Vs[rV][c8V * 8] = pv[j];
    }
    __syncthreads();   // drains vmcnt(0) -> Ms, Ks, Vs all ready

    // local QK^T (16 MFMA/wave)
    f32x4 sacc[4];
#pragma unroll
    for (int nt = 0; nt < 4; ++nt)
        sacc[nt] = (f32x4){0.f, 0.f, 0.f, 0.f};
#pragma unroll
    for (int nt = 0; nt < 4; ++nt)
#pragma unroll
        for (int ks = 0; ks < 4; ++ks) {
            half8 kf = *(const half8*)&Ks[nt * 16 + l15][ks * 32 + lq * 8];
            sacc[nt] = __builtin_amdgcn_mfma_f32_16x16x32_f16(qf[ks], kf,
                                                              sacc[nt], 0, 0, 0);
        }

    // causal mask + P -> LDS fp16
#pragma unroll
    for (int nt = 0; nt < 4; ++nt)
#pragma unroll
        for (int r = 0; r < 4; ++r) {
            int ql = w * 16 + lq * 4 + r;
            int kl = nt * 16 + l15;
            float sv = (kl <= ql) ? sacc[nt][r] : 0.f;   // same diag chunk
            Ps[ql][kl] = (_Float16)sv;
        }

    // Q·M^T (32 MFMA/wave) — Ms ready since barrier; hides Ps latency
    f32x4 oacc[8];
#pragma unroll
    for (int dt = 0; dt < 8; ++dt)
        oacc[dt] = (f32x4){0.f, 0.f, 0.f, 0.f};
#pragma unroll
    for (int dt = 0; dt < 8; ++dt)
#pragma unroll
        for (int km = 0; km < 4; ++km) {
            half8 mf = *(const half8*)&Ms[(dt * 4 + km) * 64 + lane];
            oacc[dt] = __builtin_amdgcn_mfma_f32_16x16x32_f16(qf[km], mf,
                                                              oacc[dt], 0, 0, 0);
        }
    __syncthreads();   // Ps visible to all waves

    // PV (16 MFMA/wave)
    half8 pf[2];
    pf[0] = *(const half8*)&Ps[w * 16 + l15][lq * 8];
    pf[1] = *(const half8*)&Ps[w * 16 + l15][32 + lq * 8];
#pragma unroll
    for (int dt = 0; dt < 8; ++dt)
#pragma unroll
        for (int ks = 0; ks < 2; ++ks) {
            half8 vf = *(const half8*)&Vs[dt * 16 + l15][ks * 32 + lq * 8];
            oacc[dt] = __builtin_amdgcn_mfma_f32_16x16x32_f16(pf[ks], vf,
                                                              oacc[dt], 0, 0, 0);
        }

    // epilogue: Ob (= Ks overlay, reads long done) -> coalesced half8 stores
#pragma unroll
    for (int dt = 0; dt < 8; ++dt)
#pragma unroll
        for (int r = 0; r < 4; ++r)
            Ks[w * 16 + lq * 4 + r][dt * 16 + l15] = (_Float16)oacc[dt][r];
    __syncthreads();
#pragma unroll
    for (int j = 0; j < 4; ++j) {
        int f = tid + j * 256;
        int ql = f >> 4, c8 = f & 15;
        *(uint4*)&o[(size_t)(b * S + qBase + ql) * E + h * HD + c8 * 8] =
            *(const uint4*)&Ks[ql][c8 * 8];
    }
}

// ---------------------------------------------------------------------------
extern "C" void kernel_launch(void* const* d_in, const int* in_sizes, int n_in,
                              void* d_out, int out_size, void* d_ws, size_t ws_size,
                              hipStream_t stream) {
    (void)in_sizes; (void)n_in; (void)out_size; (void)ws_size;
    const float* hs = (const float*)d_in[0];
    const float* wq = (const float*)d_in[1];
    const float* wk = (const float*)d_in[2];
    const float* wv = (const float*)d_in[3];
    const float* wo = (const float*)d_in[4];
    const float* nc = (const float*)d_in[5];
    const float* am = (const float*)d_in[6];
    const int*  pos = (const int*)d_in[7];
    float* out = (float*)d_out;

    const size_t act = (size_t)B * S * E;           // 4,194,304 (== E*E)
    _Float16* hsb = (_Float16*)d_ws;                // fp16 copies
    _Float16* wqb = hsb + act;
    _Float16* wkb = wqb + act;
    _Float16* wvb = wkb + act;
    _Float16* wob = wvb + act;
    _Float16* qhh = wob + act;                      // (b,h,s,d)
    _Float16* khh = qhh + act;
    _Float16* vhh = khh + act;                      // (b,h,s,d)
    _Float16* vtt = vhh + act;                      // (b,h,d,s)
    _Float16* abb = vtt + act;                      // attn out (b,s,E)
    // buffer reuse after gemm_qkv256 (hs/wq/wk fp16 copies dead):
    _Float16* ktt = hsb;                            // K^T (b,h,d,s), act halves
    _Float16* utm = wqb;                            // U/M^T, 2*act halves (wqb+wkb)
    // total ws unchanged: 10 * 8.39MB ~= 84 MB

    f2h5<<<dim3((int)(act / 4 / 256), 5), 256, 0, stream>>>(
        hs, wq, wk, wv, wo, hsb, wqb, wkb, wvb, wob);

    gemm_qkv256<<<192, 512, 0, stream>>>(hsb, wqb, wkb, wvb, qhh, khh, vhh);

    rotary_norm<<<(B * H * S) / 4, 256, 0, stream>>>(qhh, khh, am, pos);
    vprep<<<dim3(S / 64, B * H), 256, 0, stream>>>(vhh, khh, vtt, ktt, am, nc);

    kvouter<<<dim3(16, B * H), 256, 0, stream>>>(ktt, vtt, utm);
    prefix16<<<B * H * 8, 256, 0, stream>>>(utm);
    attn_local<<<dim3(16, B * H), 256, 0, stream>>>(qhh, khh, vtt, utm, abb);

    gemm_out<<<256, 256, 0, stream>>>(abb, wob, out);
}